// Round 5
// baseline (305.288 us; speedup 1.0000x reference)
//
#include <hip/hip_runtime.h>

namespace {

constexpr int B  = 16;
constexpr int D  = 128;
constexpr int C  = 6;
constexpr int H  = 128;
constexpr int W  = 128;
constexpr int HWC = H * W;          // 16384
constexpr int HO = 512, WO = 512;   // 4x upsample

// ---------------------------------------------------------------------------
// k_cls: px-ownership pass with DRAM-friendly staging.
// Block owns 256 px. LDS tile [32 d][256 px] (32 KB). Staging reads are
// 1 KB contiguous per wave instruction (64 lanes x float4 along px) --
// the fix for the ~2.2 TB/s ceiling every 256B/64KB-stride pattern hit.
// Dots accumulate in registers across 4 d-sub-tiles; reg-prefetch overlaps
// the next sub-tile's HBM latency with the current sub-tile's FMAs.
// Outputs: x = dot/12 + bias, class mask (byte), per-block counts.
// ---------------------------------------------------------------------------
__global__ __launch_bounds__(256) void k_cls(const float* __restrict__ assp,
                                             const float* __restrict__ cls_w,
                                             const float* __restrict__ cls_b,
                                             float* __restrict__ x,
                                             unsigned char* __restrict__ mask,
                                             int* __restrict__ counts) {
  __shared__ float tile[32 * 256];    // 32 KB

  const int t    = threadIdx.x;
  const int b    = blockIdx.y;
  const int lane = t & 63;
  const int wv   = t >> 6;
  const int px0  = blockIdx.x * 256;
  const int px   = px0 + t;

  const float* bbase = assp + ((size_t)b * D) * HWC + px0;

  // prefetch sub-tile 0: wave wv stages rows d = wv*8 + r (r=0..7)
  float4 v[8];
#pragma unroll
  for (int r = 0; r < 8; ++r)
    v[r] = *(const float4*)(bbase + (size_t)(wv * 8 + r) * HWC + lane * 4);

  float a[C] = {0.f, 0.f, 0.f, 0.f, 0.f, 0.f};

  for (int ds = 0; ds < 4; ++ds) {
    // regs -> LDS
#pragma unroll
    for (int r = 0; r < 8; ++r)
      *(float4*)&tile[(wv * 8 + r) * 256 + lane * 4] = v[r];
    __syncthreads();

    // issue next sub-tile's loads; in flight during compute
    if (ds < 3) {
      const float* nb = bbase + (size_t)((ds + 1) * 32) * HWC;
#pragma unroll
      for (int r = 0; r < 8; ++r)
        v[r] = *(const float4*)(nb + (size_t)(wv * 8 + r) * HWC + lane * 4);
    }

    // dots: thread owns px = t; column read = 2 lanes/bank (free)
#pragma unroll
    for (int dd = 0; dd < 32; ++dd) {
      float vv = tile[dd * 256 + t];
      int d = ds * 32 + dd;
#pragma unroll
      for (int c = 0; c < C; ++c) a[c] += vv * cls_w[c * D + d];
    }
    __syncthreads();                  // tile reusable
  }

  // argmax, first-wins ties == jnp.argmax
  float bv = a[0] + cls_b[0];
  int cls = 0;
#pragma unroll
  for (int c = 1; c < C; ++c) {
    float pv = a[c] + cls_b[c];
    if (pv > bv) { bv = pv; cls = c; }
  }

  // x = pseudo/12 + bias  (softmax(...,axis=1).mean(axis=1) == 1/12)
  const float inv12 = 1.0f / 12.0f;
  float* xb = x + ((size_t)b * C) * HWC + px;
#pragma unroll
  for (int c = 0; c < C; ++c) xb[(size_t)c * HWC] = a[c] * inv12 + cls_b[c];

  mask[(size_t)b * HWC + px] = (unsigned char)cls;

  // per-wave ballots -> 6 atomics per wave
  int cnt = 0;
#pragma unroll
  for (int c = 0; c < C; ++c) {
    unsigned long long m = __ballot(cls == c);
    if (lane == c) cnt = (int)__popcll(m);
  }
  if (lane < C) atomicAdd(&counts[b * C + lane], cnt);
}

// ---------------------------------------------------------------------------
// k_sum: d-ownership streaming pass, fully sequential reads.
// One wave per (b, d, 8192-px half row): float4 loads (1 KB contiguous per
// wave instr) + uchar4 mask loads; 6 register accumulators; butterfly
// reduce; 6 atomics per wave. Zero LDS, zero barriers, 4096 waves.
// ---------------------------------------------------------------------------
__global__ __launch_bounds__(256) void k_sum(const float* __restrict__ assp,
                                             const unsigned char* __restrict__ mask,
                                             float* __restrict__ sums) {
  const int t    = threadIdx.x;
  const int lane = t & 63;
  const int wv   = t >> 6;
  const int b    = blockIdx.z;
  const int d    = blockIdx.y * 4 + wv;
  const int px0  = blockIdx.x * 8192;

  const float* row = assp + ((size_t)b * D + d) * HWC + px0;
  const unsigned char* mrow = mask + (size_t)b * HWC + px0;

  float acc[C] = {0.f, 0.f, 0.f, 0.f, 0.f, 0.f};
#pragma unroll 8
  for (int i = 0; i < 32; ++i) {
    float4 vv = *(const float4*)(row + i * 256 + lane * 4);
    uchar4 mm = *(const uchar4*)(mrow + i * 256 + lane * 4);
#pragma unroll
    for (int cc = 0; cc < C; ++cc) {
      acc[cc] += (mm.x == cc) ? vv.x : 0.f;
      acc[cc] += (mm.y == cc) ? vv.y : 0.f;
      acc[cc] += (mm.z == cc) ? vv.z : 0.f;
      acc[cc] += (mm.w == cc) ? vv.w : 0.f;
    }
  }

  float out = 0.f;
#pragma unroll
  for (int cc = 0; cc < C; ++cc) {
    float s = acc[cc];
#pragma unroll
    for (int off = 32; off >= 1; off >>= 1) s += __shfl_xor(s, off, 64);
    if (lane == cc) out = s;
  }
  if (lane < C) atomicAdd(&sums[((size_t)b * C + lane) * D + d], out);
}

// ---------------------------------------------------------------------------
// K3: per dropped pixel: protoC on the fly from sums/counts, nearest proto
// (first-wins argmin == over the 12=2x6 duplicated list), patch x directly.
// one wave per (b,p); lane owns d and d+64
// ---------------------------------------------------------------------------
__global__ void k_patch(const float* __restrict__ assp,
                        const float* __restrict__ sums,
                        const int* __restrict__ counts,
                        const float* __restrict__ cls_w,
                        const float* __restrict__ cls_b,
                        const int* __restrict__ px,
                        const int* __restrict__ py,
                        int P,
                        float* __restrict__ x) {
  int bp = blockIdx.x;
  int b = bp / P, p = bp % P;
  int hw = px[p] * W + py[p];
  int lane = threadIdx.x;                  // 64 threads = 1 wave
  const float* fbase = assp + ((size_t)b * D) * HWC + hw;

  float f0 = fbase[(size_t)lane * HWC];
  float f1 = fbase[(size_t)(lane + 64) * HWC];

  float pv0[C], pv1[C], ds[C];
#pragma unroll
  for (int c = 0; c < C; ++c) {
    float cnt = (float)counts[b * C + c];
    float s0 = sums[((size_t)b * C + c) * D + lane];
    float s1 = sums[((size_t)b * C + c) * D + lane + 64];
    float q0 = (cnt > 0.f) ? s0 / (cnt + 1e-5f) : 0.f;
    float q1 = (cnt > 0.f) ? s1 / (cnt + 1e-5f) : 0.f;
    pv0[c] = q0; pv1[c] = q1;
    float e0 = q0 - f0, e1 = q1 - f1;
    float tt = e0 * e0 + e1 * e1;
#pragma unroll
    for (int off = 32; off >= 1; off >>= 1) tt += __shfl_xor(tt, off, 64);
    ds[c] = tt;                            // identical on all lanes
  }
  int best = 0; float bv = ds[0];          // first-wins ties == jnp.argmin
#pragma unroll
  for (int c = 1; c < C; ++c)
    if (ds[c] < bv) { bv = ds[c]; best = c; }

  float v0 = 0.f, v1 = 0.f;                // select without dynamic indexing
#pragma unroll
  for (int c = 0; c < C; ++c) {
    if (best == c) { v0 = pv0[c]; v1 = pv1[c]; }
  }

  float myx = 0.f;
#pragma unroll
  for (int c = 0; c < C; ++c) {
    float tt = v0 * cls_w[c * D + lane] + v1 * cls_w[c * D + lane + 64];
#pragma unroll
    for (int off = 32; off >= 1; off >>= 1) tt += __shfl_xor(tt, off, 64);
    float val = tt * (1.0f / 12.0f) + cls_b[c];
    if (lane == c) myx = val;
  }
  if (lane < C) x[((size_t)b * C + lane) * HWC + hw] = myx;
}

// ---------------------------------------------------------------------------
// K4: bilinear 4x upsample. Weights via exact integer math; <=3 input rows
// staged in LDS; 2 output rows per block; float4 coalesced stores.
// ---------------------------------------------------------------------------
__global__ __launch_bounds__(256) void k_up(const float* __restrict__ x,
                                            float* __restrict__ out) {
  __shared__ float rows[3 * W];            // 1.5 KB

  const int t = threadIdx.x;
  const size_t base = (size_t)blockIdx.x * 1024;   // first linear output index
  const int bc = (int)(base >> 18);                // output image (b*C+c)
  const int Y0 = ((int)(base >> 9)) & (HO - 1);    // first of 2 output rows

  const int ry = (Y0 * (H - 1)) / (HO - 1);        // lowest needed input row

  if (t < 96) {
    int r  = t >> 5;                               // 0..2
    int xx = (t & 31) * 4;
    int rr = ry + r; if (rr > H - 1) rr = H - 1;
    *(float4*)&rows[r * W + xx] =
        *(const float4*)(x + (size_t)bc * HWC + (size_t)rr * W + xx);
  }
  __syncthreads();

  const int h  = t >> 7;                           // which output row
  const int tt = t & 127;                          // 4 consecutive X each
  const int Y  = Y0 + h;

  const int ynum = Y * (H - 1);
  const int yl   = ynum / (HO - 1);
  const float wy = (float)((double)(ynum - yl * (HO - 1)) * (1.0 / (HO - 1)));
  int yh = yl + 1; if (yh > H - 1) yh = H - 1;
  const float* r0 = &rows[(yl - ry) * W];
  const float* r1 = &rows[(yh - ry) * W];

  float o[4];
#pragma unroll
  for (int j = 0; j < 4; ++j) {
    int X   = 4 * tt + j;
    int num = X * (W - 1);
    int lo  = num / (WO - 1);
    float wx = (float)((double)(num - lo * (WO - 1)) * (1.0 / (WO - 1)));
    int hi = lo + 1; if (hi > W - 1) hi = W - 1;

    float v00 = r0[lo], v01 = r0[hi], v10 = r1[lo], v11 = r1[hi];
    o[j] = (1.f - wy) * ((1.f - wx) * v00 + wx * v01)
         +        wy  * ((1.f - wx) * v10 + wx * v11);
  }
  float4 o4 = {o[0], o[1], o[2], o[3]};
  *(float4*)(out + base + (size_t)h * WO + 4 * tt) = o4;
}

} // namespace

extern "C" void kernel_launch(void* const* d_in, const int* in_sizes, int n_in,
                              void* d_out, int out_size, void* d_ws, size_t ws_size,
                              hipStream_t stream) {
  // inputs: assp, cls_w, cls_b, key_w, key_b, query_w, query_b, px, py
  const float* assp  = (const float*)d_in[0];
  const float* cls_w = (const float*)d_in[1];
  const float* cls_b = (const float*)d_in[2];
  const int*   px    = (const int*)d_in[7];
  const int*   py    = (const int*)d_in[8];
  const int    P     = in_sizes[7];             // 102

  // workspace layout
  char* ws = (char*)d_ws;
  float* sums            = (float*)ws;          // B*C*D = 49152 B
  int*   counts          = (int*)(ws + 49152);  // B*C*4 = 384 B
  float* x               = (float*)(ws + 65536);           // 6 MB
  unsigned char* maskbuf = (unsigned char*)(ws + 8388608); // B*HWC = 256 KB

  float* out = (float*)d_out;

  hipMemsetAsync(ws, 0, 49152 + 384, stream);
  k_cls<<<dim3(HWC / 256, B), 256, 0, stream>>>(assp, cls_w, cls_b, x, maskbuf, counts);
  k_sum<<<dim3(HWC / 8192, D / 4, B), 256, 0, stream>>>(assp, maskbuf, sums);
  k_patch<<<B * P, 64, 0, stream>>>(assp, sums, counts, cls_w, cls_b, px, py, P, x);
  k_up<<<(B * C * HO * WO) / 1024, 256, 0, stream>>>(x, out);
}

// Round 6
// 304.744 us; speedup vs baseline: 1.0018x; 1.0018x over previous
//
#include <hip/hip_runtime.h>

namespace {

constexpr int B  = 16;
constexpr int D  = 128;
constexpr int C  = 6;
constexpr int H  = 128;
constexpr int W  = 128;
constexpr int HWC = H * W;          // 16384
constexpr int HO = 512, WO = 512;   // 4x upsample

// ---------------------------------------------------------------------------
// k_dots: partial dot products with DRAM-sequential reads.
// Block = (b, d-group of 32 rows, 2048-px chunk): reads 32 rows x 8 KB
// contiguous runs (the fix for the 2.4-2.8 TB/s ceiling of 256B-1KB chunks
// at 64KB stride). Thread owns 8 px (2 float4); 48 register accumulators;
// zero LDS, zero barriers. Writes partial[b][dg][c][px] (25 MB, coalesced).
// ---------------------------------------------------------------------------
__global__ __launch_bounds__(256) void k_dots(const float* __restrict__ assp,
                                              const float* __restrict__ cls_w,
                                              float* __restrict__ partial) {
  const int t     = threadIdx.x;
  const int chunk = blockIdx.x;        // 8 chunks of 2048 px
  const int dg    = blockIdx.y;        // 4 groups of 32 d
  const int b     = blockIdx.z;
  const int px0   = chunk * 2048;

  const float* base = assp + ((size_t)b * D + dg * 32) * HWC + px0;

  const float4 z = {0.f, 0.f, 0.f, 0.f};
  float4 acc0[C] = {z, z, z, z, z, z};   // px: t*4 .. t*4+3
  float4 acc1[C] = {z, z, z, z, z, z};   // px: 1024 + t*4 ..

#pragma unroll 8
  for (int r = 0; r < 32; ++r) {
    // loads are address-independent of the FMAs -> compiler hoists them
    // ahead within each unroll window (deep vmcnt pipeline)
    float4 u0 = *(const float4*)(base + (size_t)r * HWC + t * 4);
    float4 u1 = *(const float4*)(base + (size_t)r * HWC + 1024 + t * 4);
    const int d = dg * 32 + r;
#pragma unroll
    for (int c = 0; c < C; ++c) {
      const float w = cls_w[c * D + d];       // wave-uniform -> s_load
      acc0[c].x += u0.x * w; acc0[c].y += u0.y * w;
      acc0[c].z += u0.z * w; acc0[c].w += u0.w * w;
      acc1[c].x += u1.x * w; acc1[c].y += u1.y * w;
      acc1[c].z += u1.z * w; acc1[c].w += u1.w * w;
    }
  }

  float* pb = partial + (((size_t)b * 4 + dg) * C) * HWC + px0;
#pragma unroll
  for (int c = 0; c < C; ++c) {
    *(float4*)(pb + (size_t)c * HWC + t * 4)        = acc0[c];
    *(float4*)(pb + (size_t)c * HWC + 1024 + t * 4) = acc1[c];
  }
}

// ---------------------------------------------------------------------------
// k_fin: finish per-pixel work from partials (L3-hot, 25 MB).
// s[c] = sum of 4 d-group partials; argmax (first-wins == jnp.argmax);
// x = s/12 + bias (softmax(...,axis=1).mean(axis=1) == 1/12); byte mask;
// ballot counts -> 6 atomics per wave. Zero LDS, zero barriers.
// ---------------------------------------------------------------------------
__global__ __launch_bounds__(256) void k_fin(const float* __restrict__ partial,
                                             const float* __restrict__ cls_b,
                                             float* __restrict__ x,
                                             unsigned char* __restrict__ mask,
                                             int* __restrict__ counts) {
  const int t    = threadIdx.x;
  const int b    = blockIdx.y;
  const int px   = blockIdx.x * 256 + t;
  const int lane = t & 63;

  const float* pb = partial + ((size_t)b * 4 * C) * HWC + px;
  float s[C];
#pragma unroll
  for (int c = 0; c < C; ++c)
    s[c] = pb[(size_t)(0 * C + c) * HWC] + pb[(size_t)(1 * C + c) * HWC]
         + pb[(size_t)(2 * C + c) * HWC] + pb[(size_t)(3 * C + c) * HWC];

  float bv = s[0] + cls_b[0];
  int cls = 0;
#pragma unroll
  for (int c = 1; c < C; ++c) {
    float pv = s[c] + cls_b[c];
    if (pv > bv) { bv = pv; cls = c; }
  }

  const float inv12 = 1.0f / 12.0f;
  float* xb = x + ((size_t)b * C) * HWC + px;
#pragma unroll
  for (int c = 0; c < C; ++c) xb[(size_t)c * HWC] = s[c] * inv12 + cls_b[c];

  mask[(size_t)b * HWC + px] = (unsigned char)cls;

  int cnt = 0;
#pragma unroll
  for (int c = 0; c < C; ++c) {
    unsigned long long m = __ballot(cls == c);
    if (lane == c) cnt = (int)__popcll(m);
  }
  if (lane < C) atomicAdd(&counts[b * C + lane], cnt);
}

// ---------------------------------------------------------------------------
// k_sum: d-ownership streaming pass, fully sequential reads (proven ~5.8TB/s).
// One wave per (b, d, 8192-px half row): float4 loads (1 KB contiguous per
// wave instr) + uchar4 mask loads; 6 register accumulators; butterfly
// reduce; 6 atomics per wave. Zero LDS, zero barriers.
// ---------------------------------------------------------------------------
__global__ __launch_bounds__(256) void k_sum(const float* __restrict__ assp,
                                             const unsigned char* __restrict__ mask,
                                             float* __restrict__ sums) {
  const int t    = threadIdx.x;
  const int lane = t & 63;
  const int wv   = t >> 6;
  const int b    = blockIdx.z;
  const int d    = blockIdx.y * 4 + wv;
  const int px0  = blockIdx.x * 8192;

  const float* row = assp + ((size_t)b * D + d) * HWC + px0;
  const unsigned char* mrow = mask + (size_t)b * HWC + px0;

  float acc[C] = {0.f, 0.f, 0.f, 0.f, 0.f, 0.f};
#pragma unroll 8
  for (int i = 0; i < 32; ++i) {
    float4 vv = *(const float4*)(row + i * 256 + lane * 4);
    uchar4 mm = *(const uchar4*)(mrow + i * 256 + lane * 4);
#pragma unroll
    for (int cc = 0; cc < C; ++cc) {
      acc[cc] += (mm.x == cc) ? vv.x : 0.f;
      acc[cc] += (mm.y == cc) ? vv.y : 0.f;
      acc[cc] += (mm.z == cc) ? vv.z : 0.f;
      acc[cc] += (mm.w == cc) ? vv.w : 0.f;
    }
  }

  float out = 0.f;
#pragma unroll
  for (int cc = 0; cc < C; ++cc) {
    float s = acc[cc];
#pragma unroll
    for (int off = 32; off >= 1; off >>= 1) s += __shfl_xor(s, off, 64);
    if (lane == cc) out = s;
  }
  if (lane < C) atomicAdd(&sums[((size_t)b * C + lane) * D + d], out);
}

// ---------------------------------------------------------------------------
// K3: per dropped pixel: protoC on the fly from sums/counts, nearest proto
// (first-wins argmin == over the 12=2x6 duplicated list), patch x directly.
// one wave per (b,p); lane owns d and d+64
// ---------------------------------------------------------------------------
__global__ void k_patch(const float* __restrict__ assp,
                        const float* __restrict__ sums,
                        const int* __restrict__ counts,
                        const float* __restrict__ cls_w,
                        const float* __restrict__ cls_b,
                        const int* __restrict__ px,
                        const int* __restrict__ py,
                        int P,
                        float* __restrict__ x) {
  int bp = blockIdx.x;
  int b = bp / P, p = bp % P;
  int hw = px[p] * W + py[p];
  int lane = threadIdx.x;                  // 64 threads = 1 wave
  const float* fbase = assp + ((size_t)b * D) * HWC + hw;

  float f0 = fbase[(size_t)lane * HWC];
  float f1 = fbase[(size_t)(lane + 64) * HWC];

  float pv0[C], pv1[C], ds[C];
#pragma unroll
  for (int c = 0; c < C; ++c) {
    float cnt = (float)counts[b * C + c];
    float s0 = sums[((size_t)b * C + c) * D + lane];
    float s1 = sums[((size_t)b * C + c) * D + lane + 64];
    float q0 = (cnt > 0.f) ? s0 / (cnt + 1e-5f) : 0.f;
    float q1 = (cnt > 0.f) ? s1 / (cnt + 1e-5f) : 0.f;
    pv0[c] = q0; pv1[c] = q1;
    float e0 = q0 - f0, e1 = q1 - f1;
    float tt = e0 * e0 + e1 * e1;
#pragma unroll
    for (int off = 32; off >= 1; off >>= 1) tt += __shfl_xor(tt, off, 64);
    ds[c] = tt;                            // identical on all lanes
  }
  int best = 0; float bv = ds[0];          // first-wins ties == jnp.argmin
#pragma unroll
  for (int c = 1; c < C; ++c)
    if (ds[c] < bv) { bv = ds[c]; best = c; }

  float v0 = 0.f, v1 = 0.f;                // select without dynamic indexing
#pragma unroll
  for (int c = 0; c < C; ++c) {
    if (best == c) { v0 = pv0[c]; v1 = pv1[c]; }
  }

  float myx = 0.f;
#pragma unroll
  for (int c = 0; c < C; ++c) {
    float tt = v0 * cls_w[c * D + lane] + v1 * cls_w[c * D + lane + 64];
#pragma unroll
    for (int off = 32; off >= 1; off >>= 1) tt += __shfl_xor(tt, off, 64);
    float val = tt * (1.0f / 12.0f) + cls_b[c];
    if (lane == c) myx = val;
  }
  if (lane < C) x[((size_t)b * C + lane) * HWC + hw] = myx;
}

// ---------------------------------------------------------------------------
// K4: bilinear 4x upsample. Weights via exact integer math; <=3 input rows
// staged in LDS; 2 output rows per block; float4 coalesced stores.
// ---------------------------------------------------------------------------
__global__ __launch_bounds__(256) void k_up(const float* __restrict__ x,
                                            float* __restrict__ out) {
  __shared__ float rows[3 * W];            // 1.5 KB

  const int t = threadIdx.x;
  const size_t base = (size_t)blockIdx.x * 1024;   // first linear output index
  const int bc = (int)(base >> 18);                // output image (b*C+c)
  const int Y0 = ((int)(base >> 9)) & (HO - 1);    // first of 2 output rows

  const int ry = (Y0 * (H - 1)) / (HO - 1);        // lowest needed input row

  if (t < 96) {
    int r  = t >> 5;                               // 0..2
    int xx = (t & 31) * 4;
    int rr = ry + r; if (rr > H - 1) rr = H - 1;
    *(float4*)&rows[r * W + xx] =
        *(const float4*)(x + (size_t)bc * HWC + (size_t)rr * W + xx);
  }
  __syncthreads();

  const int h  = t >> 7;                           // which output row
  const int tt = t & 127;                          // 4 consecutive X each
  const int Y  = Y0 + h;

  const int ynum = Y * (H - 1);
  const int yl   = ynum / (HO - 1);
  const float wy = (float)((double)(ynum - yl * (HO - 1)) * (1.0 / (HO - 1)));
  int yh = yl + 1; if (yh > H - 1) yh = H - 1;
  const float* r0 = &rows[(yl - ry) * W];
  const float* r1 = &rows[(yh - ry) * W];

  float o[4];
#pragma unroll
  for (int j = 0; j < 4; ++j) {
    int X   = 4 * tt + j;
    int num = X * (W - 1);
    int lo  = num / (WO - 1);
    float wx = (float)((double)(num - lo * (WO - 1)) * (1.0 / (WO - 1)));
    int hi = lo + 1; if (hi > W - 1) hi = W - 1;

    float v00 = r0[lo], v01 = r0[hi], v10 = r1[lo], v11 = r1[hi];
    o[j] = (1.f - wy) * ((1.f - wx) * v00 + wx * v01)
         +        wy  * ((1.f - wx) * v10 + wx * v11);
  }
  float4 o4 = {o[0], o[1], o[2], o[3]};
  *(float4*)(out + base + (size_t)h * WO + 4 * tt) = o4;
}

} // namespace

extern "C" void kernel_launch(void* const* d_in, const int* in_sizes, int n_in,
                              void* d_out, int out_size, void* d_ws, size_t ws_size,
                              hipStream_t stream) {
  // inputs: assp, cls_w, cls_b, key_w, key_b, query_w, query_b, px, py
  const float* assp  = (const float*)d_in[0];
  const float* cls_w = (const float*)d_in[1];
  const float* cls_b = (const float*)d_in[2];
  const int*   px    = (const int*)d_in[7];
  const int*   py    = (const int*)d_in[8];
  const int    P     = in_sizes[7];             // 102

  // workspace layout
  char* ws = (char*)d_ws;
  float* sums            = (float*)ws;          // B*C*D = 49152 B
  int*   counts          = (int*)(ws + 49152);  // B*C*4 = 384 B
  float* x               = (float*)(ws + 65536);           // 6 MB
  unsigned char* maskbuf = (unsigned char*)(ws + 8388608); // B*HWC = 256 KB
  float* partial         = (float*)(ws + 8650752);         // B*4*C*HWC*4 = 25.2 MB

  float* out = (float*)d_out;

  hipMemsetAsync(ws, 0, 49152 + 384, stream);
  k_dots<<<dim3(8, 4, B), 256, 0, stream>>>(assp, cls_w, partial);
  k_fin<<<dim3(HWC / 256, B), 256, 0, stream>>>(partial, cls_b, x, maskbuf, counts);
  k_sum<<<dim3(HWC / 8192, D / 4, B), 256, 0, stream>>>(assp, maskbuf, sums);
  k_patch<<<B * P, 64, 0, stream>>>(assp, sums, counts, cls_w, cls_b, px, py, P, x);
  k_up<<<(B * C * HO * WO) / 1024, 256, 0, stream>>>(x, out);
}